// Round 10
// baseline (406.227 us; speedup 1.0000x reference)
//
#include <hip/hip_runtime.h>

// 2-layer tanh RNN, T=2048, B=4096, I=3, H=5. f32 storage.
//
// R15 = R14 producer/consumer + three consumer-side leak fixes:
//  A: LDS h0-prefetch deepened to 2 steps (named gA/gB stage sets);
//     block-top preloads issued BEFORE the store flush so flush issue
//     (~80cy) covers their ~120cy latency.
//  B: ring row already holds units contiguously ([0:1]=(u0,u1),
//     [4:5]=(u2,u3), [6:7]=(u3,u4)) -> 3x ds_read_b64 instead of 5
//     scalar reads (one lgkmcnt wait, fewer DS ops).
//  D: __syncthreads drains vmcnt(0); R14's last out-store was issued
//     right before each barrier -> ~300-500cy store-ack wait per block,
//     paid by BOTH waves. Fix: stage the block's 8 output pairs in named
//     regs s0..s7, burst-flush at the TOP of the next consumer block
//     (stores ~800cy old at the next drain). First block peeled
//     (no flush); last block flushed after the loop.
// Producer wave (L0, quad DPP + pk, batched dwordx3 x-loads) unchanged.
// Math identical to R14 -> absmax must stay 0.00390625.

typedef float v2f  __attribute__((ext_vector_type(2)));
typedef float v2fu __attribute__((ext_vector_type(2), aligned(4)));
typedef float v3fu __attribute__((ext_vector_type(3), aligned(4)));

#define SEQ_T 2048
#define BATCH 4096
#define ISZ 3
#define HSZ 5
#define TBLK 8
#define XSTRIDE (BATCH * ISZ)
#define OSTRIDE (BATCH * HSZ)

template<int K>
__device__ __forceinline__ float qbcast(float v) {
    return __int_as_float(__builtin_amdgcn_mov_dpp(
        __float_as_int(v), K * 0x55, 0xF, 0xF, false));
}
__device__ __forceinline__ v2f vsplat(float s) { return (v2f){s, s}; }
__device__ __forceinline__ v2f vfma(float s, v2f w, v2f a) {
    return __builtin_elementwise_fma(vsplat(s), w, a);  // v_pk_fma_f32
}

__global__ __launch_bounds__(128, 1)
void rnn2_pc2(const float* __restrict__ x, const float* __restrict__ hx,
              const float* __restrict__ w_ih0, const float* __restrict__ w_hh0,
              const float* __restrict__ b_ih0, const float* __restrict__ b_hh0,
              const float* __restrict__ w_ih1, const float* __restrict__ w_hh1,
              const float* __restrict__ b_ih1, const float* __restrict__ b_hh1,
              float* __restrict__ out)
{
    // ring[buf][step][chain_local][12]: 48B rows, 8B-aligned b64 ops.
    __shared__ float ring[2][TBLK][16][12];

    const int tid  = threadIdx.x;
    const int wid  = tid >> 6;                      // 0 = L0 prod, 1 = L1 cons
    const int lane = tid & 63;
    const int cl   = lane >> 2;                     // chain-local 0..15
    const int ja   = lane & 3;                      // slot A unit
    const int jb   = ja + 1;                        // slot B unit
    const int c    = blockIdx.x * 16 + cl;          // chain id
    const float S  = 2.8853900817779268f;           // 2*log2(e)

    const v2f bias0p = (v2f){ S * (b_ih0[ja] + b_hh0[ja]), S * (b_ih0[jb] + b_hh0[jb]) };
    const v2f bias1p = (v2f){ S * (b_ih1[ja] + b_hh1[ja]), S * (b_ih1[jb] + b_hh1[jb]) };
#define LW(W, k, n)  (v2f){ S * W[ja * (n) + (k)], S * W[jb * (n) + (k)] }
    const v2f wi0p0 = LW(w_ih0, 0, ISZ), wi0p1 = LW(w_ih0, 1, ISZ), wi0p2 = LW(w_ih0, 2, ISZ);
    const v2f wh0p0 = LW(w_hh0, 0, HSZ), wh0p1 = LW(w_hh0, 1, HSZ), wh0p2 = LW(w_hh0, 2, HSZ),
              wh0p3 = LW(w_hh0, 3, HSZ), wh0p4 = LW(w_hh0, 4, HSZ);
    const v2f wi1p0 = LW(w_ih1, 0, HSZ), wi1p1 = LW(w_ih1, 1, HSZ), wi1p2 = LW(w_ih1, 2, HSZ),
              wi1p3 = LW(w_ih1, 3, HSZ), wi1p4 = LW(w_ih1, 4, HSZ);
    const v2f wh1p0 = LW(w_hh1, 0, HSZ), wh1p1 = LW(w_hh1, 1, HSZ), wh1p2 = LW(w_hh1, 2, HSZ),
              wh1p3 = LW(w_hh1, 3, HSZ), wh1p4 = LW(w_hh1, 4, HSZ);
#undef LW

    float h0b0 = hx[(size_t)c * HSZ + 0], h0b1 = hx[(size_t)c * HSZ + 1],
          h0b2 = hx[(size_t)c * HSZ + 2], h0b3 = hx[(size_t)c * HSZ + 3],
          h0b4 = hx[(size_t)c * HSZ + 4];
    const size_t hb1 = (size_t)BATCH * HSZ + (size_t)c * HSZ;
    float h1b0 = hx[hb1 + 0], h1b1 = hx[hb1 + 1], h1b2 = hx[hb1 + 2],
          h1b3 = hx[hb1 + 3], h1b4 = hx[hb1 + 4];

    // ---- producer x block buffers ----
    unsigned xoff = (unsigned)c * ISZ;
    v3fu xA0, xA1, xA2, xA3, xA4, xA5, xA6, xA7;
    v3fu xB0, xB1, xB2, xB3, xB4, xB5, xB6, xB7;
#define LOADX(P)                                                           \
    {                                                                      \
        P##0 = *(const v3fu*)(x + xoff + 0*XSTRIDE);                       \
        P##1 = *(const v3fu*)(x + xoff + 1*XSTRIDE);                       \
        P##2 = *(const v3fu*)(x + xoff + 2*XSTRIDE);                       \
        P##3 = *(const v3fu*)(x + xoff + 3*XSTRIDE);                       \
        P##4 = *(const v3fu*)(x + xoff + 4*XSTRIDE);                       \
        P##5 = *(const v3fu*)(x + xoff + 5*XSTRIDE);                       \
        P##6 = *(const v3fu*)(x + xoff + 6*XSTRIDE);                       \
        P##7 = *(const v3fu*)(x + xoff + 7*XSTRIDE);                       \
        xoff += 8u * XSTRIDE;                                              \
    }

    unsigned ooff = (unsigned)c * HSZ + (unsigned)ja;   // consumer out ptr
    v2f gA01, gA23, gA34, gB01, gB23, gB34;             // h0 stages (A)
    v2f s0, s1, s2, s3, s4, s5, s6, s7;                 // out staging (D)

// producer step (unchanged from R14)
#define STEP0(XV, WR, TT)                                                  \
    {                                                                      \
        v2f a = bias0p, cc = (v2f){0.0f, 0.0f};                            \
        a  = vfma(XV.x,  wi0p0, a);                                        \
        cc = vfma(XV.y,  wi0p1, cc);                                       \
        a  = vfma(XV.z,  wi0p2, a);                                        \
        cc = vfma(h0b0, wh0p0, cc);                                        \
        a  = vfma(h0b1, wh0p1, a);                                         \
        cc = vfma(h0b2, wh0p2, cc);                                        \
        a  = vfma(h0b3, wh0p3, a);                                         \
        cc = vfma(h0b4, wh0p4, cc);                                        \
        a = a + cc;                                                        \
        v2f e0;                                                            \
        e0.x = __builtin_amdgcn_exp2f(a.x);                                \
        e0.y = __builtin_amdgcn_exp2f(a.y);                                \
        const v2f p0 = e0 + vsplat(1.0f);                                  \
        v2f r0;                                                            \
        r0.x = __builtin_amdgcn_rcpf(p0.x);                                \
        r0.y = __builtin_amdgcn_rcpf(p0.y);                                \
        const v2f n0 = __builtin_elementwise_fma(vsplat(-2.0f), r0, vsplat(1.0f)); \
        h0b0 = qbcast<0>(n0.x);                                            \
        h0b1 = qbcast<1>(n0.x);                                            \
        h0b2 = qbcast<2>(n0.x);                                            \
        h0b3 = qbcast<3>(n0.x);                                            \
        h0b4 = qbcast<3>(n0.y);                                            \
        *(v2f*)&WR[TT][cl][ja * 2] = n0;                                   \
    }

#define PBLOCK(P, RB)                                                      \
    {                                                                      \
        float (*wr)[16][12] = ring[RB];                                    \
        STEP0(P##0, wr, 0)                                                 \
        STEP0(P##1, wr, 1)                                                 \
        STEP0(P##2, wr, 2)                                                 \
        STEP0(P##3, wr, 3)                                                 \
        STEP0(P##4, wr, 4)                                                 \
        STEP0(P##5, wr, 5)                                                 \
        STEP0(P##6, wr, 6)                                                 \
        STEP0(P##7, wr, 7)                                                 \
    }

// consumer step: consume stage (UG*), optional 2-ahead prefetch into them,
// stage result into SREG. Dot order identical to R14.
#define STEP1(UG01, UG23, UG34, RD, PT, DOPRE, SREG)                       \
    {                                                                      \
        const float u0 = UG01.x, u1 = UG01.y, u2 = UG23.x,                 \
                    u3 = UG23.y, u4 = UG34.y;                              \
        if (DOPRE) {                                                       \
            UG01 = *(const v2f*)&RD[PT][cl][0];                            \
            UG23 = *(const v2f*)&RD[PT][cl][4];                            \
            UG34 = *(const v2f*)&RD[PT][cl][6];                            \
        }                                                                  \
        v2f d = bias1p, ee = (v2f){0.0f, 0.0f};                            \
        d  = vfma(u0,   wi1p0, d);                                         \
        ee = vfma(u1,   wi1p1, ee);                                        \
        d  = vfma(u2,   wi1p2, d);                                         \
        ee = vfma(u3,   wi1p3, ee);                                        \
        d  = vfma(u4,   wi1p4, d);                                         \
        ee = vfma(h1b0, wh1p0, ee);                                        \
        d  = vfma(h1b1, wh1p1, d);                                         \
        ee = vfma(h1b2, wh1p2, ee);                                        \
        d  = vfma(h1b3, wh1p3, d);                                         \
        ee = vfma(h1b4, wh1p4, ee);                                        \
        d = d + ee;                                                        \
        v2f e1;                                                            \
        e1.x = __builtin_amdgcn_exp2f(d.x);                                \
        e1.y = __builtin_amdgcn_exp2f(d.y);                                \
        const v2f p1 = e1 + vsplat(1.0f);                                  \
        v2f r1;                                                            \
        r1.x = __builtin_amdgcn_rcpf(p1.x);                                \
        r1.y = __builtin_amdgcn_rcpf(p1.y);                                \
        const v2f n1 = __builtin_elementwise_fma(vsplat(-2.0f), r1, vsplat(1.0f)); \
        SREG = n1;                                                         \
        h1b0 = qbcast<0>(n1.x);                                            \
        h1b1 = qbcast<1>(n1.x);                                            \
        h1b2 = qbcast<2>(n1.x);                                            \
        h1b3 = qbcast<3>(n1.x);                                            \
        h1b4 = qbcast<3>(n1.y);                                            \
    }

// flush previous block's staged outputs (issued right AFTER a barrier)
#define FLUSH()                                                            \
    {                                                                      \
        *(v2fu*)(out + ooff) = s0; ooff += OSTRIDE;                        \
        *(v2fu*)(out + ooff) = s1; ooff += OSTRIDE;                        \
        *(v2fu*)(out + ooff) = s2; ooff += OSTRIDE;                        \
        *(v2fu*)(out + ooff) = s3; ooff += OSTRIDE;                        \
        *(v2fu*)(out + ooff) = s4; ooff += OSTRIDE;                        \
        *(v2fu*)(out + ooff) = s5; ooff += OSTRIDE;                        \
        *(v2fu*)(out + ooff) = s6; ooff += OSTRIDE;                        \
        *(v2fu*)(out + ooff) = s7; ooff += OSTRIDE;                        \
    }

// consumer block: preload 2 stages, then flush prev block, then 8 steps
#define CBLOCK(RB, DOFLUSH)                                                \
    {                                                                      \
        const float (*rd)[16][12] = ring[RB];                              \
        gA01 = *(const v2f*)&rd[0][cl][0];                                 \
        gA23 = *(const v2f*)&rd[0][cl][4];                                 \
        gA34 = *(const v2f*)&rd[0][cl][6];                                 \
        gB01 = *(const v2f*)&rd[1][cl][0];                                 \
        gB23 = *(const v2f*)&rd[1][cl][4];                                 \
        gB34 = *(const v2f*)&rd[1][cl][6];                                 \
        if (DOFLUSH) FLUSH()                                               \
        STEP1(gA01, gA23, gA34, rd, 2, 1, s0)                              \
        STEP1(gB01, gB23, gB34, rd, 3, 1, s1)                              \
        STEP1(gA01, gA23, gA34, rd, 4, 1, s2)                              \
        STEP1(gB01, gB23, gB34, rd, 5, 1, s3)                              \
        STEP1(gA01, gA23, gA34, rd, 6, 1, s4)                              \
        STEP1(gB01, gB23, gB34, rd, 7, 1, s5)                              \
        STEP1(gA01, gA23, gA34, rd, 7, 0, s6)                              \
        STEP1(gB01, gB23, gB34, rd, 7, 0, s7)                              \
    }

    // ---- prologue ----
    LOADX(xA)
    __syncthreads();
    if (wid == 0) { LOADX(xB) PBLOCK(xA, 0) }          // producer block 0

    // peeled pair 0: consumer block 0 must not flush
    __syncthreads();
    if (wid == 0) { LOADX(xA) PBLOCK(xB, 1) } else { CBLOCK(0, 0) }
    __syncthreads();
    if (wid == 0) { LOADX(xB) PBLOCK(xA, 0) } else { CBLOCK(1, 1) }

    // steady pairs: sp = 1..126
    for (int sp = 1; sp < 127; ++sp) {
        __syncthreads();
        if (wid == 0) { LOADX(xA) PBLOCK(xB, 1) } else { CBLOCK(0, 1) }
        __syncthreads();
        if (wid == 0) { LOADX(xB) PBLOCK(xA, 0) } else { CBLOCK(1, 1) }
    }

    // producer's last block (255); consumer block 254
    __syncthreads();
    if (wid == 0) { PBLOCK(xB, 1) } else { CBLOCK(0, 1) }

    // consumer drains block 255, then flushes its staged outputs
    __syncthreads();
    if (wid != 0) { CBLOCK(1, 1) FLUSH() }

#undef STEP0
#undef STEP1
#undef PBLOCK
#undef CBLOCK
#undef FLUSH
#undef LOADX

    // h_n = [h0_final, h1_final] after out[T,B,H]; quad-dup stores benign
    float* hn = out + (size_t)SEQ_T * BATCH * HSZ;
    if (wid == 0) {
        hn[(size_t)c * HSZ + 0] = h0b0;
        hn[(size_t)c * HSZ + 1] = h0b1;
        hn[(size_t)c * HSZ + 2] = h0b2;
        hn[(size_t)c * HSZ + 3] = h0b3;
        hn[(size_t)c * HSZ + 4] = h0b4;
    } else {
        hn[hb1 + 0] = h1b0;
        hn[hb1 + 1] = h1b1;
        hn[hb1 + 2] = h1b2;
        hn[hb1 + 3] = h1b3;
        hn[hb1 + 4] = h1b4;
    }
}

extern "C" void kernel_launch(void* const* d_in, const int* in_sizes, int n_in,
                              void* d_out, int out_size, void* d_ws, size_t ws_size,
                              hipStream_t stream) {
    // 256 blocks x 128 threads: 16 chains/block; wave0 = L0, wave1 = L1.
    rnn2_pc2<<<BATCH / 16, 128, 0, stream>>>(
        (const float*)d_in[0], (const float*)d_in[1],
        (const float*)d_in[2], (const float*)d_in[3],
        (const float*)d_in[4], (const float*)d_in[5],
        (const float*)d_in[6], (const float*)d_in[7],
        (const float*)d_in[8], (const float*)d_in[9],
        (float*)d_out);
}